// Round 7
// baseline (229.365 us; speedup 1.0000x reference)
//
#include <hip/hip_runtime.h>
#include <math.h>

#define S 4096
#define N_NODES 2048
#define N_CHILD 4096
#define NNZ 32768
#define NNZ_TOTAL (2 * NNZ)
#define TSM 512    // samples per main block
#define TN 8       // nodes per main block
#define CAP 96     // padded-row capacity (mean 32; +11 sigma)
#define LP 516     // lds row pitch (floats) in main

typedef float f32x2 __attribute__((ext_vector_type(2)));

// ---- prep: blocks 0..63 scatter entries to padded rows; 64..2111 exp+transpose
// ET layout: ET[(m*N_CHILD + c)*S + s] = fp8_e4m3(exp(ll_m[s, c]))
// texp block bits (bt = b-64): [0:2]=slice (XCD pin), [3]=sthalf, [4:9]=ct, [10]=z

__global__ __launch_bounds__(1024, 8) void prep_kernel(
        const float* __restrict__ ll0, const float* __restrict__ ll1,
        const float* __restrict__ w0d, const float* __restrict__ w1d,
        const int* __restrict__ w0r, const int* __restrict__ w0c,
        const int* __restrict__ w1r, const int* __restrict__ w1c,
        unsigned char* __restrict__ ET, int2* __restrict__ ent,
        int* __restrict__ counts) {
    __shared__ unsigned short tile[64 * 130];   // 16640 B
    int t = threadIdx.x;
    int b = blockIdx.x;
    if (b < 64) {
        int k = b * 1024 + t;
        int row, col; float w;
        if (k < NNZ) { row = w0r[k]; col = w0c[k]; w = w0d[k]; }
        else { int kk = k - NNZ; row = w1r[kk]; col = w1c[kk] + N_CHILD; w = w1d[kk]; }
        int pos = atomicAdd(&counts[row], 1);
        if (pos < CAP)
            ent[row * CAP + pos] = make_int2(col, __float_as_int(__expf(w)));
        return;
    }
    int bt = b - 64;
    int slice = bt & 7;
    int sthalf = (bt >> 3) & 1;
    int ct = (bt >> 4) & 63;
    int z = (bt >> 10) & 1;
    int c0 = ct * 64;
    int s0 = slice * 512 + sthalf * 256;
    const float* ll = z ? ll1 : ll0;
    int wave = t >> 6, lane = t & 63;
    // preload ALL 16 values; sched_barrier pins the loads BEFORE any exp work
    float v0[8], v1[8];
    const float* p = ll + (size_t)(s0 + wave * 2) * N_CHILD + c0 + lane;
#pragma unroll
    for (int it = 0; it < 8; ++it) {
        v0[it] = p[0];
        v1[it] = p[N_CHILD];
        p += 32 * (size_t)N_CHILD;
    }
    __builtin_amdgcn_sched_barrier(0);   // 16 loads in flight before first vmcnt wait
#pragma unroll
    for (int it = 0; it < 8; ++it) {
        int sh = it * 16 + wave;          // sample-pair 0..127
        unsigned int packed = (unsigned int)__builtin_amdgcn_cvt_pk_fp8_f32(
            __expf(v0[it]), __expf(v1[it]), 0, false);
        tile[lane * 130 + sh] = (unsigned short)packed;   // 2-way bank alias: free
    }
    __syncthreads();
    unsigned char* dst = ET + (size_t)(z * N_CHILD + c0) * S + s0;
#pragma unroll
    for (int it = 0; it < 4; ++it) {
        int c = it * 16 + wave;
        unsigned int v = *(const unsigned int*)&tile[c * 130 + lane * 2];
        *(unsigned int*)(dst + (size_t)c * S + lane * 4) = v;   // 256 B/wave contiguous
    }
}

// ---- main: out[s,i] = log(sum_k ET[col_k,s]*ew_k) - log(sum_k ew_k) --------

static __device__ inline void fma16(uint4 x, float w, float* a) {
#pragma unroll
    for (int q = 0; q < 4; ++q) {
        unsigned int word = (q == 0) ? x.x : (q == 1) ? x.y : (q == 2) ? x.z : x.w;
        f32x2 lo = __builtin_amdgcn_cvt_pk_f32_fp8(word, false);
        f32x2 hi = __builtin_amdgcn_cvt_pk_f32_fp8(word, true);
        a[q * 4 + 0] = fmaf(lo.x, w, a[q * 4 + 0]);
        a[q * 4 + 1] = fmaf(lo.y, w, a[q * 4 + 1]);
        a[q * 4 + 2] = fmaf(hi.x, w, a[q * 4 + 2]);
        a[q * 4 + 3] = fmaf(hi.y, w, a[q * 4 + 3]);
    }
}

// Broadcast this half's entry hs+2*t2 from the register-held row.
// CALLER GUARANTEES all 64 lanes are active (wave-uniform loop bound): a
// ds_bpermute from an exec-masked source lane is undefined — that was the
// round-6 bug. Out-of-range entries (k >= cnt) are neutralized: w=0, col
// masked in-bounds so the dead gather is safe.
static __device__ inline void entry_get(int t2, int hs, int cnt, int2 eA, int2 eB,
                                        int& col, float& w) {
    int k = hs + 2 * t2;
    int c, wi;
    if (t2 < 32) { c = __shfl(eA.x, k); wi = __shfl(eA.y, k); }
    else         { c = __shfl(eB.x, k - 64); wi = __shfl(eB.y, k - 64); }
    col = c & (2 * N_CHILD - 1);
    w = (k < cnt) ? __uint_as_float(wi) : 0.f;
}

__global__ __launch_bounds__(256, 4) void main_kernel(
        const unsigned char* __restrict__ ET, const int2* __restrict__ ent,
        const int* __restrict__ counts, float* __restrict__ out) {
    __shared__ float lds[TN * LP];    // [node][sample] 16512 B
    int t = threadIdx.x, wave = t >> 6, lane = t & 63;
    int hs = lane >> 5, sl = lane & 31;   // half-wave split: even/odd entries
    int slice = blockIdx.x & 7;           // XCD pin: 4 MB fp8 ET slice per XCD L2
    int nb = blockIdx.x >> 3;
    int i0 = nb * TN;
    const unsigned char* ETs = ET + slice * TSM + sl * 16;   // lane covers 16 samples
    for (int jj = 0; jj < 2; ++jj) {
        int j = wave * 2 + jj;            // each wave owns 2 nodes
        int i = i0 + j;
        int cnt = __builtin_amdgcn_readfirstlane(counts[i]);
        if (cnt > CAP) cnt = CAP;
        const int2* eb = ent + i * CAP;
        // whole entry row -> registers (one-time); kills the per-iter dependent load
        int2 eA = eb[lane];               // entries 0..63
        int2 eB = eb[64 + (lane & 31)];   // entries 64..95
        float a[16];
#pragma unroll
        for (int u = 0; u < 16; ++u) a[u] = 0.f;
        float z = 0.f;
        int nmax = (cnt + 1) >> 1;        // WAVE-UNIFORM bound: both halves iterate it
        int t2 = 0;
        for (; t2 + 3 < nmax; t2 += 4) {  // 4 x 16B loads in flight per lane
            int c0i, c1i, c2i, c3i; float w0, w1, w2, w3;
            entry_get(t2 + 0, hs, cnt, eA, eB, c0i, w0);
            entry_get(t2 + 1, hs, cnt, eA, eB, c1i, w1);
            entry_get(t2 + 2, hs, cnt, eA, eB, c2i, w2);
            entry_get(t2 + 3, hs, cnt, eA, eB, c3i, w3);
            uint4 x0 = *(const uint4*)(ETs + (size_t)c0i * S);
            uint4 x1 = *(const uint4*)(ETs + (size_t)c1i * S);
            uint4 x2 = *(const uint4*)(ETs + (size_t)c2i * S);
            uint4 x3 = *(const uint4*)(ETs + (size_t)c3i * S);
            fma16(x0, w0, a); fma16(x1, w1, a);
            fma16(x2, w2, a); fma16(x3, w3, a);
            z += w0 + w1 + w2 + w3;
        }
        for (; t2 < nmax; ++t2) {
            int c0i; float w0;
            entry_get(t2, hs, cnt, eA, eB, c0i, w0);
            uint4 x0 = *(const uint4*)(ETs + (size_t)c0i * S);
            fma16(x0, w0, a);
            z += w0;
        }
        // cross-half reduction: lanes l and l^32 hold partials of same outputs
#pragma unroll
        for (int u = 0; u < 16; ++u) a[u] += __shfl_xor(a[u], 32);
        z += __shfl_xor(z, 32);
        float lz = __logf(z);
        float r[8];
#pragma unroll
        for (int u = 0; u < 8; ++u) r[u] = __logf(a[hs * 8 + u]) - lz;
        float* dstl = &lds[j * LP + sl * 16 + hs * 8];
        *(float4*)(dstl)     = make_float4(r[0], r[1], r[2], r[3]);
        *(float4*)(dstl + 4) = make_float4(r[4], r[5], r[6], r[7]);
    }
    __syncthreads();
    // out write: 512 samples x 8 nodes, NT so the stream doesn't evict ET from L2
    float* obase = out + (size_t)slice * TSM * N_NODES + i0;
#pragma unroll
    for (int q = 0; q < 8; ++q) {
        int elem = (t + 256 * q) * 2;
        int s_l = elem >> 3;
        int i_l = elem & 7;
        f32x2 v;
        v.x = lds[i_l * LP + s_l];
        v.y = lds[(i_l + 1) * LP + s_l];
        __builtin_nontemporal_store(v, (f32x2*)&obase[(size_t)s_l * N_NODES + i_l]);
    }
}

// ---- launch ---------------------------------------------------------------

extern "C" void kernel_launch(void* const* d_in, const int* in_sizes, int n_in,
                              void* d_out, int out_size, void* d_ws, size_t ws_size,
                              hipStream_t stream) {
    const float* ll0 = (const float*)d_in[0];
    const float* ll1 = (const float*)d_in[1];
    const float* w0d = (const float*)d_in[2];
    const float* w1d = (const float*)d_in[3];
    const int*   w0r = (const int*)d_in[4];
    const int*   w0c = (const int*)d_in[5];
    const int*   w1r = (const int*)d_in[6];
    const int*   w1c = (const int*)d_in[7];
    float* out = (float*)d_out;

    unsigned char* ET = (unsigned char*)d_ws;                    // 32 MiB
    int2* ent   = (int2*)(ET + (size_t)2 * N_CHILD * S);         // 2048*96*8 B
    int*  counts = (int*)(ent + (size_t)N_NODES * CAP);          // 2048

    hipMemsetAsync(counts, 0, sizeof(int) * N_NODES, stream);
    prep_kernel<<<2112, 1024, 0, stream>>>(ll0, ll1, w0d, w1d, w0r, w0c, w1r, w1c,
                                           ET, ent, counts);
    main_kernel<<<(N_NODES / TN) * (S / TSM), 256, 0, stream>>>(ET, ent, counts, out);
}